// Round 2
// 6478.259 us; speedup vs baseline: 2.2657x; 2.2657x over previous
//
#include <hip/hip_runtime.h>
#include <math.h>

#define NB 8      // batch
#define SEQ 512   // LD == LE
#define DIM 512   // D
#define NH 8
#define HD 64
#define FFD 2048
#define NLAYER 6

// ---------------- embedding + sinusoidal position ----------------
__global__ __launch_bounds__(256) void embed_kernel(
    const int* __restrict__ dec, const float* __restrict__ emb, float* __restrict__ X)
{
    int idx = blockIdx.x * 256 + threadIdx.x;   // over NB*SEQ*DIM
    int d  = idx & (DIM - 1);
    int row = idx >> 9;           // b*SEQ + l
    int l  = row & (SEQ - 1);
    int tok = dec[row];
    double e = (double)(2 * (d >> 1)) / (double)DIM;
    double ang = (double)(l + 1) * pow(10000.0, -e);
    float pv = (float)((d & 1) ? cos(ang) : sin(ang));
    X[idx] = emb[(size_t)tok * DIM + d] + pv;
}

__global__ __launch_bounds__(256) void copy_kernel(const float* __restrict__ s, float* __restrict__ d)
{
    int i = blockIdx.x * 256 + threadIdx.x;
    d[i] = s[i];
}

// ---------------- GEMM: C[M,N] = A[M,K] * W[N,K]^T + bias, optional relu ----
__global__ __launch_bounds__(256) void gemm_nt(
    const float* __restrict__ A, const float* __restrict__ W,
    const float* __restrict__ bias, float* __restrict__ C,
    int M, int N, int K, int relu)
{
    __shared__ float As[16][68];
    __shared__ float Ws[16][68];
    const int tid = threadIdx.x;
    const int tx = tid & 15, ty = tid >> 4;
    const int m0 = blockIdx.y * 64, n0 = blockIdx.x * 64;
    float acc[4][4] = {};

    for (int k0 = 0; k0 < K; k0 += 16) {
#pragma unroll
        for (int p = 0; p < 4; ++p) {
            int e = tid + 256 * p;      // 0..1023
            int r = e >> 4, c = e & 15;
            As[c][r] = A[(size_t)(m0 + r) * K + k0 + c];
            Ws[c][r] = W[(size_t)(n0 + r) * K + k0 + c];
        }
        __syncthreads();
#pragma unroll
        for (int kk = 0; kk < 16; ++kk) {
            const float4 a4 = *(const float4*)&As[kk][ty * 4];
            const float4 w4 = *(const float4*)&Ws[kk][tx * 4];
            float av[4] = {a4.x, a4.y, a4.z, a4.w};
            float wv[4] = {w4.x, w4.y, w4.z, w4.w};
#pragma unroll
            for (int i = 0; i < 4; ++i)
#pragma unroll
                for (int j = 0; j < 4; ++j)
                    acc[i][j] += av[i] * wv[j];
        }
        __syncthreads();
    }

    float bv[4];
#pragma unroll
    for (int j = 0; j < 4; ++j) bv[j] = bias[n0 + tx * 4 + j];
#pragma unroll
    for (int i = 0; i < 4; ++i) {
        int m = m0 + ty * 4 + i;
        float4 o;
        float* po = (float*)&o;
#pragma unroll
        for (int j = 0; j < 4; ++j) {
            float v = acc[i][j] + bv[j];
            if (relu) v = fmaxf(v, 0.f);
            po[j] = v;
        }
        *(float4*)&C[(size_t)m * N + n0 + tx * 4] = o;
    }
}

// ---------------- attention phase 1: raw masked scores --------------------
// S[bh, q, k] = 0.125 * Q[b,q,h,:]·K[b,k,h,:]  (masked -> -1e9)
// grid: (SEQ/64, SEQ/64, NB*NH), block 256.  K=64 single LDS stage.
__global__ __launch_bounds__(256) void attn_scores(
    const float* __restrict__ Q, const float* __restrict__ Kb,
    const int* __restrict__ toks, float* __restrict__ Sout, int causal)
{
    __shared__ float Qs[64][68];   // k-major: Qs[d][q]
    __shared__ float Ks[64][68];   // k-major: Ks[d][k]
    const int tid = threadIdx.x;
    const int tx = tid & 15, ty = tid >> 4;
    const int kt = blockIdx.x * 64, qt = blockIdx.y * 64;
    const int bh = blockIdx.z, b = bh >> 3, h = bh & 7;

    float* sp = Sout + ((size_t)bh * SEQ + qt) * SEQ + kt;

    // fully-masked causal tile: fill -1e9 and exit (44% of self-attn tiles)
    if (causal && kt >= qt + 64) {
        const float4 neg = make_float4(-1e9f, -1e9f, -1e9f, -1e9f);
#pragma unroll
        for (int p = 0; p < 4; ++p) {
            int e = tid + 256 * p;        // 0..1023 float4s
            int r = e >> 4, c4 = e & 15;
            *(float4*)&sp[(size_t)r * SEQ + c4 * 4] = neg;
        }
        return;
    }

    const float* qbase = Q  + ((size_t)(b * SEQ + qt)) * DIM + h * HD;
    const float* kbase = Kb + ((size_t)(b * SEQ + kt)) * DIM + h * HD;
#pragma unroll
    for (int p = 0; p < 16; ++p) {
        int e = tid + 256 * p;       // 0..4095
        int r = e >> 6, c = e & 63;  // consecutive lanes -> consecutive c: coalesced
        Qs[c][r] = qbase[(size_t)r * DIM + c];
        Ks[c][r] = kbase[(size_t)r * DIM + c];
    }
    __syncthreads();

    float acc[4][4] = {};
#pragma unroll
    for (int kk = 0; kk < 64; ++kk) {
        const float4 a4 = *(const float4*)&Qs[kk][ty * 4];
        const float4 w4 = *(const float4*)&Ks[kk][tx * 4];
        float av[4] = {a4.x, a4.y, a4.z, a4.w};
        float wv[4] = {w4.x, w4.y, w4.z, w4.w};
#pragma unroll
        for (int i = 0; i < 4; ++i)
#pragma unroll
            for (int j = 0; j < 4; ++j)
                acc[i][j] += av[i] * wv[j];
    }

#pragma unroll
    for (int i = 0; i < 4; ++i) {
        int q = qt + ty * 4 + i;
        float4 o;
        float* po = (float*)&o;
#pragma unroll
        for (int j = 0; j < 4; ++j) {
            int k = kt + tx * 4 + j;
            bool masked = (toks[b * SEQ + k] == 0) || (causal && k > q);
            po[j] = masked ? -1e9f : acc[i][j] * 0.125f;
        }
        *(float4*)&sp[(size_t)(ty * 4 + i) * SEQ + tx * 4] = o;
    }
}

// ---------------- attention phase 2: in-place row softmax (rows of 512) ----
// one wave per row, 4 rows per block
__global__ __launch_bounds__(256) void softmax512(float* __restrict__ W)
{
    const int lane = threadIdx.x & 63;
    const int wv = threadIdx.x >> 6;
    float* p = W + ((size_t)blockIdx.x * 4 + wv) * SEQ;
    float4 a = *(float4*)&p[lane * 4];
    float4 b = *(float4*)&p[lane * 4 + 256];
    float mx = fmaxf(fmaxf(fmaxf(a.x, a.y), fmaxf(a.z, a.w)),
                     fmaxf(fmaxf(b.x, b.y), fmaxf(b.z, b.w)));
#pragma unroll
    for (int st = 1; st < 64; st <<= 1) mx = fmaxf(mx, __shfl_xor(mx, st));
    a.x = expf(a.x - mx); a.y = expf(a.y - mx); a.z = expf(a.z - mx); a.w = expf(a.w - mx);
    b.x = expf(b.x - mx); b.y = expf(b.y - mx); b.z = expf(b.z - mx); b.w = expf(b.w - mx);
    float sum = a.x + a.y + a.z + a.w + b.x + b.y + b.z + b.w;
#pragma unroll
    for (int st = 1; st < 64; st <<= 1) sum += __shfl_xor(sum, st);
    float inv = 1.f / sum;
    a.x *= inv; a.y *= inv; a.z *= inv; a.w *= inv;
    b.x *= inv; b.y *= inv; b.z *= inv; b.w *= inv;
    *(float4*)&p[lane * 4] = a;
    *(float4*)&p[lane * 4 + 256] = b;
}

// ---------------- attention phase 3: CTX = W · V ---------------------------
// per (b,h): [512x512]·[512x64]; grid (SEQ/64, NB*NH), block 256
__global__ __launch_bounds__(256) void attn_ctx(
    const float* __restrict__ W, const float* __restrict__ Vb, float* __restrict__ CTX)
{
    __shared__ float Ws[16][68];   // k-major: Ws[k][q]
    __shared__ float Vs[16][68];   // Vs[k][d]
    const int tid = threadIdx.x;
    const int tx = tid & 15, ty = tid >> 4;
    const int qt = blockIdx.x * 64;
    const int bh = blockIdx.y, b = bh >> 3, h = bh & 7;
    const float* wbase = W + ((size_t)bh * SEQ + qt) * SEQ;
    const float* vbase = Vb + ((size_t)(b * SEQ)) * DIM + h * HD;
    float acc[4][4] = {};

    for (int k0 = 0; k0 < SEQ; k0 += 16) {
#pragma unroll
        for (int p = 0; p < 4; ++p) {
            int e = tid + 256 * p;          // 0..1023
            int r = e >> 4, c = e & 15;     // 64 q-rows x 16 k
            Ws[c][r] = wbase[(size_t)r * SEQ + k0 + c];
            int rk = e >> 6, cd = e & 63;   // 16 k-rows x 64 d (coalesced)
            Vs[rk][cd] = vbase[(size_t)(k0 + rk) * DIM + cd];
        }
        __syncthreads();
#pragma unroll
        for (int kk = 0; kk < 16; ++kk) {
            const float4 a4 = *(const float4*)&Ws[kk][ty * 4];
            const float4 v4 = *(const float4*)&Vs[kk][tx * 4];
            float av[4] = {a4.x, a4.y, a4.z, a4.w};
            float vv[4] = {v4.x, v4.y, v4.z, v4.w};
#pragma unroll
            for (int i = 0; i < 4; ++i)
#pragma unroll
                for (int j = 0; j < 4; ++j)
                    acc[i][j] += av[i] * vv[j];
        }
        __syncthreads();
    }

#pragma unroll
    for (int i = 0; i < 4; ++i) {
        float4 o = make_float4(acc[i][0], acc[i][1], acc[i][2], acc[i][3]);
        *(float4*)&CTX[((size_t)(b * SEQ + qt + ty * 4 + i)) * DIM + h * HD + tx * 4] = o;
    }
}

// ---------------- residual add + layernorm ----------------
__global__ __launch_bounds__(256) void add_ln(
    const float* __restrict__ Xin, const float* __restrict__ O,
    const float* __restrict__ g, const float* __restrict__ bt,
    float* Xout)
{
    const int row = blockIdx.x, tid = threadIdx.x;
    __shared__ float red[256];
    const size_t base = (size_t)row * DIM;
    float v0 = Xin[base + tid] + O[base + tid];
    float v1 = Xin[base + tid + 256] + O[base + tid + 256];
    red[tid] = v0 + v1; __syncthreads();
    for (int st = 128; st; st >>= 1) { if (tid < st) red[tid] += red[tid + st]; __syncthreads(); }
    float mean = red[0] * (1.f / 512.f); __syncthreads();
    red[tid] = v0 * v0 + v1 * v1; __syncthreads();
    for (int st = 128; st; st >>= 1) { if (tid < st) red[tid] += red[tid + st]; __syncthreads(); }
    float var = red[0] * (1.f / 512.f) - mean * mean;
    float rst = rsqrtf(var + 1e-5f);
    Xout[base + tid]       = (v0 - mean) * rst * g[tid]       + bt[tid];
    Xout[base + tid + 256] = (v1 - mean) * rst * g[tid + 256] + bt[tid + 256];
}

// ---------------- host orchestration ----------------
extern "C" void kernel_launch(void* const* d_in, const int* in_sizes, int n_in,
                              void* d_out, int out_size, void* d_ws, size_t ws_size,
                              hipStream_t stream)
{
    const int*   dec     = (const int*)d_in[0];
    const int*   enc     = (const int*)d_in[1];
    const float* enc_out = (const float*)d_in[2];
    const float* emb     = (const float*)d_in[3];
    const float* sa_wq = (const float*)d_in[4];
    const float* sa_wk = (const float*)d_in[5];
    const float* sa_wv = (const float*)d_in[6];
    const float* sa_wo = (const float*)d_in[7];
    const float* sa_bq = (const float*)d_in[8];
    const float* sa_bk = (const float*)d_in[9];
    const float* sa_bv = (const float*)d_in[10];
    const float* sa_bo = (const float*)d_in[11];
    const float* sa_g  = (const float*)d_in[12];
    const float* sa_b  = (const float*)d_in[13];
    const float* ca_wq = (const float*)d_in[14];
    const float* ca_wk = (const float*)d_in[15];
    const float* ca_wv = (const float*)d_in[16];
    const float* ca_wo = (const float*)d_in[17];
    const float* ca_bq = (const float*)d_in[18];
    const float* ca_bk = (const float*)d_in[19];
    const float* ca_bv = (const float*)d_in[20];
    const float* ca_bo = (const float*)d_in[21];
    const float* ca_g  = (const float*)d_in[22];
    const float* ca_b  = (const float*)d_in[23];
    const float* ffn_w1 = (const float*)d_in[24];
    const float* ffn_b1 = (const float*)d_in[25];
    const float* ffn_w2 = (const float*)d_in[26];
    const float* ffn_b2 = (const float*)d_in[27];
    const float* ffn_g  = (const float*)d_in[28];
    const float* ffn_b  = (const float*)d_in[29];

    float* out = (float*)d_out;
    const size_t NTOK = (size_t)NB * SEQ;        // 4096 rows
    const size_t NELT = NTOK * DIM;              // 2,097,152
    const size_t DD = (size_t)DIM * DIM;         // 262,144

    float* X    = (float*)d_ws;
    float* A1   = X    + NELT;    // Q   (FFN hidden overlays A1..A4)
    float* A2   = A1   + NELT;    // K
    float* A3   = A2   + NELT;    // V
    float* A4   = A3   + NELT;    // CTX
    float* A5   = A4   + NELT;    // attn/FFN output before LN
    float* Fb   = A1;             // [4096, 2048] fp32 FFN hidden

    const size_t SA_BASE = NELT;                          // 2,097,152
    const size_t PER_L   = (size_t)NB * NH * SEQ * SEQ;   // 16,777,216
    const size_t CA_BASE = SA_BASE + (size_t)NLAYER * PER_L;

    dim3 blk(256);
    dim3 g_elem((unsigned)(NELT / 256));
    dim3 g_gemm_d(DIM / 64, (unsigned)(NTOK / 64));   // (8, 64)
    dim3 g_gemm_f(FFD / 64, (unsigned)(NTOK / 64));   // (32, 64)
    dim3 g_sc(SEQ / 64, SEQ / 64, NB * NH);           // (8, 8, 64)
    dim3 g_sm((unsigned)(NB * NH * SEQ / 4));         // 8192
    dim3 g_ctx(SEQ / 64, NB * NH);                    // (8, 64)

    embed_kernel<<<g_elem, blk, 0, stream>>>(dec, emb, X);

    for (int l = 0; l < NLAYER; ++l) {
        // ---- self-attention ----
        float* Wsa = out + SA_BASE + (size_t)l * PER_L;
        gemm_nt<<<g_gemm_d, blk, 0, stream>>>(X, sa_wq + l * DD, sa_bq + l * DIM, A1, (int)NTOK, DIM, DIM, 0);
        gemm_nt<<<g_gemm_d, blk, 0, stream>>>(X, sa_wk + l * DD, sa_bk + l * DIM, A2, (int)NTOK, DIM, DIM, 0);
        gemm_nt<<<g_gemm_d, blk, 0, stream>>>(X, sa_wv + l * DD, sa_bv + l * DIM, A3, (int)NTOK, DIM, DIM, 0);
        attn_scores<<<g_sc, blk, 0, stream>>>(A1, A2, dec, Wsa, 1);
        softmax512<<<g_sm, blk, 0, stream>>>(Wsa);
        attn_ctx<<<g_ctx, blk, 0, stream>>>(Wsa, A3, A4);
        gemm_nt<<<g_gemm_d, blk, 0, stream>>>(A4, sa_wo + l * DD, sa_bo + l * DIM, A5, (int)NTOK, DIM, DIM, 0);
        add_ln<<<dim3((unsigned)NTOK), blk, 0, stream>>>(X, A5, sa_g + l * DIM, sa_b + l * DIM, X);

        // ---- cross-attention ----
        float* Wca = out + CA_BASE + (size_t)l * PER_L;
        gemm_nt<<<g_gemm_d, blk, 0, stream>>>(X,       ca_wq + l * DD, ca_bq + l * DIM, A1, (int)NTOK, DIM, DIM, 0);
        gemm_nt<<<g_gemm_d, blk, 0, stream>>>(enc_out, ca_wk + l * DD, ca_bk + l * DIM, A2, (int)NTOK, DIM, DIM, 0);
        gemm_nt<<<g_gemm_d, blk, 0, stream>>>(enc_out, ca_wv + l * DD, ca_bv + l * DIM, A3, (int)NTOK, DIM, DIM, 0);
        attn_scores<<<g_sc, blk, 0, stream>>>(A1, A2, enc, Wca, 0);
        softmax512<<<g_sm, blk, 0, stream>>>(Wca);
        attn_ctx<<<g_ctx, blk, 0, stream>>>(Wca, A3, A4);
        gemm_nt<<<g_gemm_d, blk, 0, stream>>>(A4, ca_wo + l * DD, ca_bo + l * DIM, A5, (int)NTOK, DIM, DIM, 0);
        add_ln<<<dim3((unsigned)NTOK), blk, 0, stream>>>(X, A5, ca_g + l * DIM, ca_b + l * DIM, X);

        // ---- FFN ----
        gemm_nt<<<g_gemm_f, blk, 0, stream>>>(X,  ffn_w1 + l * (size_t)FFD * DIM, ffn_b1 + l * FFD, Fb, (int)NTOK, FFD, DIM, 1);
        gemm_nt<<<g_gemm_d, blk, 0, stream>>>(Fb, ffn_w2 + l * (size_t)DIM * FFD, ffn_b2 + l * DIM, A5, (int)NTOK, DIM, FFD, 0);
        add_ln<<<dim3((unsigned)NTOK), blk, 0, stream>>>(X, A5, ffn_g + l * DIM, ffn_b + l * DIM, X);
    }

    copy_kernel<<<g_elem, blk, 0, stream>>>(X, out);
}